// Round 1
// 258.979 us; speedup vs baseline: 1.0087x; 1.0087x over previous
//
#include <hip/hip_runtime.h>
#include <hip/hip_fp16.h>

// GCN encoder: 3x (GCNConv + ReLU), dims 256->128->64->32
// N=50000 nodes, E=800000 edges. edge_index delivered as int32 (harness).
// R2: CSR gather.  R3/R11: multi-block scan, fused.  R4: packed deg+cnt atomic.
// R5: fp16 H buffers.  R6: MFMA gemms.  R7: atomic-free fill via rank.
// R10: persistent-B gemm.  R11: agg software-pipelined.
// R12: gemm1 fused INTO the histogram kernel.
// R13: (a) pk replicated 4x (rep = e&3) to cut per-address atomic contention;
//          per-replica rank + packed repbase offsets reconstruct CSR slots.
//      (b) gemm2/gemm3 fused into agg1/agg2 epilogues: post-ReLU rows staged
//          in LDS, per-block MFMA (M=16 slabs) on the otherwise-idle matrix
//          pipe. Kills 2 dispatches, the out1 round-trip, and the standalone
//          gemms' 4x-redundant A re-reads. Numerics bit-identical.

#define D0 256
#define D1 128
#define D2 64
#define D3 32

#define NREP 4                          // pk replicas (contention / 4)

#define FIX_SCALE 16777216.0f           // 2^24 fixed-point for degree
#define FIX_INV   (1.0f / 16777216.0f)

typedef _Float16 half8 __attribute__((ext_vector_type(8)));
typedef float floatx4 __attribute__((ext_vector_type(4)));

// ------------------------------------------------------ gemm device core ---
// H[N,BN] (fp16) = X[N,K] @ W[K,BN] (both possibly fp32, cvt in-register).
// A[m=lane&15][k=quad*8+j]; B[k][n]; D row=quad*4+reg.
template <typename SRC>
__device__ __forceinline__ half8 loadA(const SRC* __restrict__ p) {
    if constexpr (sizeof(SRC) == 4) {
        float4 f0 = *(const float4*)p;
        float4 f1 = *(const float4*)(p + 4);
        half8 v;
        v[0] = (_Float16)f0.x; v[1] = (_Float16)f0.y;
        v[2] = (_Float16)f0.z; v[3] = (_Float16)f0.w;
        v[4] = (_Float16)f1.x; v[5] = (_Float16)f1.y;
        v[6] = (_Float16)f1.z; v[7] = (_Float16)f1.w;
        return v;
    } else {
        return *(const half8*)p;
    }
}

template <int K, int BN, typename SRC>
__device__ __forceinline__ void gemm_work(const SRC* __restrict__ X,
                                          const float* __restrict__ W,
                                          _Float16* __restrict__ H, int N,
                                          int w, int totalWaves) {
    constexpr int NC = K / 32;        // k-chunks
    constexpr int CG = BN / 32;       // col groups (waves per slab)
    const int lane = threadIdx.x & 63;
    const int quad = lane >> 4;
    const int m = lane & 15;
    const int cg = w & (CG - 1);
    const int nslab = N >> 4;         // N multiple of 16
    const int stride = totalWaves / CG;
    int slab = w / CG;
    if (slab >= nslab) return;
    const int n0 = cg * 32;

    // ---- persistent B-frags: W fp32, strided, loaded once per wave ----
    half8 b0[NC], b1[NC];
#pragma unroll
    for (int c = 0; c < NC; ++c) {
#pragma unroll
        for (int j = 0; j < 8; ++j) {
            int k = c * 32 + quad * 8 + j;
            b0[c][j] = (_Float16)W[(size_t)k * BN + n0 + m];
            b1[c][j] = (_Float16)W[(size_t)k * BN + n0 + 16 + m];
        }
    }

    half8 a[NC];
#pragma unroll
    for (int c = 0; c < NC; ++c)
        a[c] = loadA(&X[(size_t)(slab * 16 + m) * K + c * 32 + quad * 8]);

    while (true) {
        const int next = slab + stride;
        half8 an[NC];
        if (next < nslab) {
#pragma unroll
            for (int c = 0; c < NC; ++c)
                an[c] = loadA(&X[(size_t)(next * 16 + m) * K + c * 32 + quad * 8]);
        }

        floatx4 acc0 = (floatx4){0.f, 0.f, 0.f, 0.f};
        floatx4 acc1 = (floatx4){0.f, 0.f, 0.f, 0.f};
#pragma unroll
        for (int c = 0; c < NC; ++c) {
            acc0 = __builtin_amdgcn_mfma_f32_16x16x32_f16(a[c], b0[c], acc0, 0, 0, 0);
            acc1 = __builtin_amdgcn_mfma_f32_16x16x32_f16(a[c], b1[c], acc1, 0, 0, 0);
        }

        const int r0 = slab * 16 + quad * 4;
#pragma unroll
        for (int r = 0; r < 4; ++r) {
            H[(size_t)(r0 + r) * BN + n0 + m]      = (_Float16)acc0[r];
            H[(size_t)(r0 + r) * BN + n0 + 16 + m] = (_Float16)acc1[r];
        }

        if (next >= nslab) break;
        slab = next;
#pragma unroll
        for (int c = 0; c < NC; ++c) a[c] = an[c];
    }
}

// ------------------------------- fused histogram + gemm1 (independent) -----
// Blocks [0,gB): gemm1 (x fp32 @ W1 fp32 -> h1 fp16).
// Blocks [gB,..): packed deg+cnt atomic histogram into replica (e&3);
// old>>32 = per-replica edge rank.
__global__ __launch_bounds__(256) void hist_gemm1_kernel(
        const float* __restrict__ x, const float* __restrict__ W1,
        _Float16* __restrict__ h1, int N,
        const int* __restrict__ ei, const float* __restrict__ ew,
        unsigned long long* __restrict__ pk, int* __restrict__ rank, int E,
        int gB) {
    const int b = blockIdx.x;
    if (b < gB) {
        gemm_work<D0, D1, float>(x, W1, h1, N, b * 4 + (threadIdx.x >> 6), gB * 4);
    } else {
        int e = (b - gB) * 256 + threadIdx.x;
        if (e < E) {
            int c = ei[E + e];
            int rep = e & (NREP - 1);
            unsigned int wfix = (unsigned int)(ew[e] * FIX_SCALE + 0.5f);
            unsigned long long old =
                atomicAdd(&pk[(size_t)rep * N + c],
                          (1ULL << 32) | (unsigned long long)wfix);
            rank[e] = (int)(old >> 32);
        }
    }
}

// --------------------------------------------- 2-phase exclusive scan ------
// Reduces the NREP replicas: deg = sum of fixed-point parts (+1 self loop),
// cnt = total count, repbase = packed per-replica exclusive bases (u8 each).
__global__ __launch_bounds__(256) void scan_reduce(const unsigned long long* __restrict__ pk,
                                                   float* __restrict__ dinv,
                                                   int* __restrict__ cnt,
                                                   unsigned* __restrict__ repbase,
                                                   int* __restrict__ blockSum, int N) {
    __shared__ int s[256];
    const int t = threadIdx.x;
    const int i = blockIdx.x * 256 + t;
    int v = 0;
    if (i < N) {
        unsigned long long p0 = pk[i];
        unsigned long long p1 = pk[(size_t)N + i];
        unsigned long long p2 = pk[(size_t)2 * N + i];
        unsigned long long p3 = pk[(size_t)3 * N + i];
        unsigned ws = (unsigned)p0 + (unsigned)p1 + (unsigned)p2 + (unsigned)p3;
        float d = (float)ws * FIX_INV + 1.0f;   // +1 self-loop
        dinv[i] = rsqrtf(d);
        int c0 = (int)(p0 >> 32), c1 = (int)(p1 >> 32);
        int c2 = (int)(p2 >> 32), c3 = (int)(p3 >> 32);
        v = c0 + c1 + c2 + c3;
        cnt[i] = v;
        repbase[i] = (unsigned)c0 | ((unsigned)(c0 + c1) << 8) |
                     ((unsigned)(c0 + c1 + c2) << 16);
    }
    s[t] = v;
    __syncthreads();
#pragma unroll
    for (int off = 128; off > 0; off >>= 1) {
        if (t < off) s[t] += s[t + off];
        __syncthreads();
    }
    if (t == 0) blockSum[blockIdx.x] = s[0];
}

__global__ __launch_bounds__(256) void scan_apply(const int* __restrict__ cnt,
                                                  const int* __restrict__ blockSum,
                                                  int* __restrict__ row_ptr, int N, int B) {
    __shared__ int bs[256];
    __shared__ int s[256];
    const int t = threadIdx.x;
    bs[t] = (t < B) ? blockSum[t] : 0;
    __syncthreads();
#pragma unroll
    for (int off = 1; off < 256; off <<= 1) {
        int u = (t >= off) ? bs[t - off] : 0;
        __syncthreads();
        bs[t] += u;
        __syncthreads();
    }
    const int myOff = (blockIdx.x > 0) ? bs[blockIdx.x - 1] : 0;
    const int i = blockIdx.x * 256 + t;
    const int v = (i < N) ? cnt[i] : 0;
    s[t] = v;
    __syncthreads();
#pragma unroll
    for (int off = 1; off < 256; off <<= 1) {
        int u = (t >= off) ? s[t - off] : 0;
        __syncthreads();
        s[t] += u;
        __syncthreads();
    }
    if (i < N) row_ptr[i] = s[t] - v + myOff;
    if (blockIdx.x == 0 && t == 0) row_ptr[N] = bs[B - 1];
}

// ------------------------------------------------- bucket fill (CSR) -------
__global__ void fill_kernel(const int* __restrict__ ei, const float* __restrict__ ew,
                            const float* __restrict__ dinv,
                            const int* __restrict__ row_ptr, const int* __restrict__ rank,
                            const unsigned* __restrict__ repbase,
                            int2* __restrict__ pairs, int E) {
    int e = blockIdx.x * blockDim.x + threadIdx.x;
    if (e < E) {
        int r = ei[e];
        int c = ei[E + e];
        float w = dinv[r] * ew[e] * dinv[c];
        int rep = e & (NREP - 1);
        unsigned rb = repbase[c];
        int base = rep ? (int)((rb >> ((rep - 1) * 8)) & 0xffu) : 0;
        pairs[row_ptr[c] + base + rank[e]] = make_int2(r, __float_as_int(w));
    }
}

// ------------------------- fused aggregate + epilogue + NEXT-LAYER gemm ----
// Gather/scale/bias/relu as before, but the post-ReLU rows are staged in LDS
// and each block runs the next layer's gemm with MFMA (M=16 row slabs).
// Hout[n] = relu_row(n) @ W  (fp16 A and B, fp32 acc — identical numerics to
// the standalone mfma_gemm path this replaces).
template <int DIN, int DOUT>
__global__ __launch_bounds__(256) void agg_gemm_kernel(
        const _Float16* __restrict__ H, const int* __restrict__ row_ptr,
        const int2* __restrict__ pairs, const float* __restrict__ dinv,
        const float* __restrict__ bias, const float* __restrict__ W,
        _Float16* __restrict__ Hout, int N) {
    constexpr int TPN = DIN / 8;      // threads per node
    constexpr int NPB = 256 / TPN;    // nodes per block
    constexpr int NC  = DIN / 32;     // gemm k-chunks
    constexpr int S   = NPB / 16;     // 16-row slabs per block
    constexpr int T   = DOUT / 16;    // 16-col tiles
    static_assert(S * T == 4, "one tile per wave");
    // +8 halves pad: rows stay 16B-aligned for ds_read_b128; 2-way bank alias
    // (free) instead of 16-way.
    __shared__ _Float16 sA[NPB][DIN + 8];

    const int tid = threadIdx.x;
    const int g = tid / TPN;
    const int sl = tid % TPN;
    const int node0 = blockIdx.x * NPB;
    const int node = node0 + g;
    const bool valid = node < N;

    // ---- hoisted B-frags (fp32 W, loop-invariant; loads hide under gather) --
    const int w = tid >> 6;
    const int lane = tid & 63;
    const int q = lane >> 4;
    const int m = lane & 15;
    const int s = w & (S - 1);
    const int t = w / S;
    half8 bf[NC];
#pragma unroll
    for (int c = 0; c < NC; ++c) {
#pragma unroll
        for (int j = 0; j < 8; ++j)
            bf[c][j] = (_Float16)W[(size_t)(c * 32 + q * 8 + j) * DOUT + t * 16 + m];
    }

    float acc[8];
#pragma unroll
    for (int j = 0; j < 8; ++j) acc[j] = 0.0f;

    int beg = 0, end = 0;
    if (valid) { beg = row_ptr[node]; end = row_ptr[node + 1]; }

    if (end > beg) {
        const int last = end - 1;
        int2 p0 = pairs[beg];
        int2 p1 = pairs[min(beg + 1, last)];
        int2 p2 = pairs[min(beg + 2, last)];
        half8 u0 = *(const half8*)&H[(size_t)p0.x * DIN + sl * 8];
        half8 u1 = *(const half8*)&H[(size_t)p1.x * DIN + sl * 8];
        for (int k = beg; k < end; ++k) {
            int2 p3 = pairs[min(k + 3, last)];
            half8 u2 = *(const half8*)&H[(size_t)p2.x * DIN + sl * 8];
            float wv = __int_as_float(p0.y);
#pragma unroll
            for (int j = 0; j < 8; ++j) acc[j] = fmaf(wv, (float)u0[j], acc[j]);
            p0 = p1; p1 = p2; p2 = p3;
            u0 = u1; u1 = u2;
        }
    }

    if (valid) {
        // self-loop + bias + relu -> LDS (this IS the out row, fp16)
        float di = dinv[node];
        float d2 = di * di;
        half8 u = *(const half8*)&H[(size_t)node * DIN + sl * 8];
#pragma unroll
        for (int j = 0; j < 8; ++j) acc[j] = fmaf(d2, (float)u[j], acc[j]);
        float bb[8];
        *(float4*)&bb[0] = *(const float4*)&bias[sl * 8];
        *(float4*)&bb[4] = *(const float4*)&bias[sl * 8 + 4];
        half8 o;
#pragma unroll
        for (int j = 0; j < 8; ++j) o[j] = (_Float16)fmaxf(acc[j] + bb[j], 0.f);
        *(half8*)&sA[g][sl * 8] = o;
    }
    __syncthreads();

    // ---- next-layer gemm on the block's rows ----
    half8 a[NC];
#pragma unroll
    for (int c = 0; c < NC; ++c)
        a[c] = *(const half8*)&sA[s * 16 + m][c * 32 + q * 8];
    floatx4 o4 = (floatx4){0.f, 0.f, 0.f, 0.f};
#pragma unroll
    for (int c = 0; c < NC; ++c)
        o4 = __builtin_amdgcn_mfma_f32_16x16x32_f16(a[c], bf[c], o4, 0, 0, 0);
#pragma unroll
    for (int r = 0; r < 4; ++r) {
        const int nr = node0 + s * 16 + q * 4 + r;
        if (nr < N) Hout[(size_t)nr * DOUT + t * 16 + m] = (_Float16)o4[r];
    }
}

// -------------------------------------- final aggregate + epilogue (fp32) --
template <int D, typename OUT>
__global__ __launch_bounds__(256) void agg_kernel(const _Float16* __restrict__ H,
                                                  const int* __restrict__ row_ptr,
                                                  const int2* __restrict__ pairs,
                                                  const float* __restrict__ dinv,
                                                  const float* __restrict__ bias,
                                                  OUT* __restrict__ out, int N) {
    constexpr int TPN = D / 8;
    constexpr int NPB = 256 / TPN;
    const int tid = threadIdx.x;
    const int g = tid / TPN;
    const int lane = tid % TPN;
    const int node = blockIdx.x * NPB + g;
    if (node >= N) return;

    const int beg = row_ptr[node];
    const int end = row_ptr[node + 1];
    float acc[8];
#pragma unroll
    for (int j = 0; j < 8; ++j) acc[j] = 0.0f;

    if (end > beg) {
        const int last = end - 1;
        int2 p0 = pairs[beg];
        int2 p1 = pairs[min(beg + 1, last)];
        int2 p2 = pairs[min(beg + 2, last)];
        half8 u0 = *(const half8*)&H[(size_t)p0.x * D + lane * 8];
        half8 u1 = *(const half8*)&H[(size_t)p1.x * D + lane * 8];
        for (int k = beg; k < end; ++k) {
            int2 p3 = pairs[min(k + 3, last)];
            half8 u2 = *(const half8*)&H[(size_t)p2.x * D + lane * 8];
            float w = __int_as_float(p0.y);
#pragma unroll
            for (int j = 0; j < 8; ++j) acc[j] = fmaf(w, (float)u0[j], acc[j]);
            p0 = p1; p1 = p2; p2 = p3;
            u0 = u1; u1 = u2;
        }
    }
    float di = dinv[node];
    float d2 = di * di;
    {
        half8 u = *(const half8*)&H[(size_t)node * D + lane * 8];
#pragma unroll
        for (int j = 0; j < 8; ++j) acc[j] = fmaf(d2, (float)u[j], acc[j]);
    }
    float b[8];
    *(float4*)&b[0] = *(const float4*)&bias[lane * 8];
    *(float4*)&b[4] = *(const float4*)&bias[lane * 8 + 4];
#pragma unroll
    for (int j = 0; j < 8; ++j) acc[j] = fmaxf(acc[j] + b[j], 0.f);

    if constexpr (sizeof(OUT) == 2) {
        half8 o;
#pragma unroll
        for (int j = 0; j < 8; ++j) o[j] = (_Float16)acc[j];
        *(half8*)&out[(size_t)node * D + lane * 8] = o;
    } else {
        float* dst = (float*)&out[(size_t)node * D + lane * 8];
        *(float4*)&dst[0] = make_float4(acc[0], acc[1], acc[2], acc[3]);
        *(float4*)&dst[4] = make_float4(acc[4], acc[5], acc[6], acc[7]);
    }
}

// ---------------------------------------------------------------- launch ----
extern "C" void kernel_launch(void* const* d_in, const int* in_sizes, int n_in,
                              void* d_out, int out_size, void* d_ws, size_t ws_size,
                              hipStream_t stream) {
    const float* x   = (const float*)d_in[0];
    const int* ei    = (const int*)d_in[1];
    const float* ew  = (const float*)d_in[2];
    const float* W1  = (const float*)d_in[3];
    const float* b1  = (const float*)d_in[4];
    const float* W2  = (const float*)d_in[5];
    const float* b2  = (const float*)d_in[6];
    const float* W3  = (const float*)d_in[7];
    const float* b3  = (const float*)d_in[8];
    float* out = (float*)d_out;

    const int N = in_sizes[0] / D0;   // 50000
    const int E = in_sizes[2];        // 800000
    (void)n_in; (void)out_size; (void)ws_size;

    // ---- workspace carving ----
    char* ws = (char*)d_ws;
    size_t off = 0;
    auto carve = [&](size_t bytes) -> void* {
        void* p = (void*)(ws + off);
        off += (bytes + 255) & ~(size_t)255;
        return p;
    };
    unsigned long long* pk = (unsigned long long*)carve((size_t)N * NREP * 8);
    float* dinv    = (float*)carve((size_t)N * 4);
    int*   cnt     = (int*)carve((size_t)N * 4);
    int*   row_ptr = (int*)carve((size_t)(N + 1) * 4);
    int*   rank    = (int*)carve((size_t)E * 4);
    int*   bsum    = (int*)carve(256 * 4);
    unsigned* repbase = (unsigned*)carve((size_t)N * 4);
    int2*  pairs   = (int2*)carve((size_t)E * 8);
    _Float16* bufH = (_Float16*)carve((size_t)N * D1 * 2);
    _Float16* bufO = (_Float16*)carve((size_t)N * D1 * 2);

    _Float16* h1 = bufH;              // N x 128 fp16 (gemm1 out)
    _Float16* h2 = bufO;              // N x 64  fp16 (agg1+gemm2 out)
    _Float16* h3 = bufH;              // N x 32  fp16 (agg2+gemm3 out; h1 dead)

    const int eb = (E + 255) / 256;       // 3125
    const int scanB = (N + 255) / 256;    // 196 (must be <= 256)
    const int gB = 768;                   // gemm blocks (3/CU, 3072 waves)

    // ---- fused: gemm1 + replicated histogram (independent, one dispatch) ----
    hipMemsetAsync(pk, 0, (size_t)N * NREP * 8, stream);
    hist_gemm1_kernel<<<gB + eb, 256, 0, stream>>>(
        x, W1, h1, N, ei, ew, pk, rank, E, gB);

    // ---- CSR build ----
    scan_reduce<<<scanB, 256, 0, stream>>>(pk, dinv, cnt, repbase, bsum, N);
    scan_apply<<<scanB, 256, 0, stream>>>(cnt, bsum, row_ptr, N, scanB);
    fill_kernel<<<eb, 256, 0, stream>>>(ei, ew, dinv, row_ptr, rank, repbase, pairs, E);

    // ---- layer 1 aggregate (+ fused gemm2: 128 -> 64) ----
    agg_gemm_kernel<D1, D2><<<(N + 15) / 16, 256, 0, stream>>>(
        h1, row_ptr, pairs, dinv, b1, W2, h2, N);

    // ---- layer 2 aggregate (+ fused gemm3: 64 -> 32) ----
    agg_gemm_kernel<D2, D3><<<(N + 31) / 32, 256, 0, stream>>>(
        h2, row_ptr, pairs, dinv, b2, W3, h3, N);

    // ---- layer 3 aggregate + epilogue (fp32 out) ----
    agg_kernel<D3, float><<<(N + 63) / 64, 256, 0, stream>>>(
        h3, row_ptr, pairs, dinv, b3, out, N);
}